// Round 8
// baseline (490.927 us; speedup 1.0000x reference)
//
#include <hip/hip_runtime.h>
#include <hip/hip_bf16.h>

// GlobalAttn: x = lrelu(concat(q,k) @ w1^T + b1); attn[e,h] = x[e,h,:]·w2[h,:];
// out = segment_softmax(attn, index). E=320000, D=256, K=512, H=4, N=10000.
//
// R8: barrier-free, LDS-free GEMM. Evidence: all R1-R7 structures were
// orchestration-bound (every pipe <20%); pipe demands are MFMA 10us, VALU
// ~5us vs HBM 104us floor. A's MFMA fragment is read DIRECTLY from global
// fp32 (per step+row the wave consumes exactly one 128-B line: cols
// s*32..s*32+31, lhi-group j takes floats j*8..j*8+7) -> single-touch,
// line-granular, no staging. B from frag-ordered wf table (256 KB, L2-hot).
// No LDS, no barriers, no vmcnt drains: waves fully independent, compiler
// pipelines the unrolled load/cvt/MFMA stream, TLP (16 waves/CU) does the rest.
// Unified VGPR/AGPR budget (R7 lesson): acc[2][4]=32 AGPR + ~80 arch ≈ 112
// <= 128 -> launch_bounds(512,4) with NO spill (validate: WRITE_SIZE ~6 MB).
// 8 waves = 2 row-halves x 4 heads; wave tile 32x64; grid 5000.

typedef __attribute__((ext_vector_type(8))) short bf16x8;
typedef __attribute__((ext_vector_type(4))) float f32x4;

#define NNODES 10000

__device__ __forceinline__ short f2bf(float f) {
    __hip_bfloat16 h = __float2bfloat16(f);   // RNE
    return *reinterpret_cast<short*>(&h);
}

// ---- B prep: fragment-ordered bf16 (one-time, tiny) ----
// frag id f = c*16 + s (c: 16-col block 0..15, s: 32-k slice 0..15).
// wf[(f*64 + lane)*8 + j] = bf16( w1[c*16 + (lane&15)][s*32 + (lane>>4)*8 + j] )
__global__ void w1_frag(const float* __restrict__ w1, short* __restrict__ wf) {
    int bid = blockIdx.x;            // 0..255 = c*16 + s
    int l   = threadIdx.x;           // 0..63
    int n = (bid >> 4) * 16 + (l & 15);
    int k = (bid & 15) * 32 + (l >> 4) * 8;
    const float* src = w1 + (size_t)n * 512 + k;
    float4 v0 = *(const float4*)src;
    float4 v1 = *(const float4*)(src + 4);
    bf16x8 pk;
    pk[0]=f2bf(v0.x); pk[1]=f2bf(v0.y); pk[2]=f2bf(v0.z); pk[3]=f2bf(v0.w);
    pk[4]=f2bf(v1.x); pk[5]=f2bf(v1.y); pk[6]=f2bf(v1.z); pk[7]=f2bf(v1.w);
    *(bf16x8*)(wf + ((size_t)bid * 64 + l) * 8) = pk;
}

__global__ void seg_init(float* __restrict__ segsum, int n) {
    int i = blockIdx.x * blockDim.x + threadIdx.x;
    if (i < n) segsum[i] = 0.f;
}

// ---------------- main fused GEMM + epilogue ----------------
__global__ __launch_bounds__(512, 4) void attn_gemm(
    const float* __restrict__ q, const float* __restrict__ kk_,
    const short* __restrict__ wf, const float* __restrict__ b1,
    const float* __restrict__ w2, const int* __restrict__ index,
    float* __restrict__ attn, float* __restrict__ segsum)
{
    const int tid  = threadIdx.x;
    const int lane = tid & 63;
    const int w    = tid >> 6;        // 8 waves
    const int hd   = w & 3;           // head 0..3 (64 cols each)
    const int wm   = w >> 2;          // row half 0..1 (32 rows each)
    const int l15  = lane & 15;
    const int lhi  = lane >> 4;
    const int row0 = blockIdx.x * 64; // 5000 blocks

    f32x4 acc[2][4];
#pragma unroll
    for (int i = 0; i < 2; ++i)
#pragma unroll
        for (int j = 0; j < 4; ++j) acc[i][j] = (f32x4){0.f, 0.f, 0.f, 0.f};

    // A: lane-invariant row offsets (floats); step adds (s&7)*32
    const size_t aoff0 = (size_t)(row0 + wm * 32 + l15) * 256 + lhi * 8;
    const size_t aoff1 = aoff0 + 16 * 256;
    // B: frag (hd*4+fn)*16 + s at stride 512 shorts
    const short* wfb = wf + (size_t)(hd * 64) * 512 + lane * 8;

#pragma unroll
    for (int s = 0; s < 16; ++s) {
        const float* ab = (s < 8) ? q : kk_;
        const int ko = (s & 7) * 32;

        bf16x8 bfr[4];
#pragma unroll
        for (int fn = 0; fn < 4; ++fn)
            bfr[fn] = *(const bf16x8*)(wfb + (fn * 16 + s) * 512);

        bf16x8 a0, a1;
        {
            float4 v0 = *(const float4*)(ab + aoff0 + ko);
            float4 v1 = *(const float4*)(ab + aoff0 + ko + 4);
            a0[0]=f2bf(v0.x); a0[1]=f2bf(v0.y); a0[2]=f2bf(v0.z); a0[3]=f2bf(v0.w);
            a0[4]=f2bf(v1.x); a0[5]=f2bf(v1.y); a0[6]=f2bf(v1.z); a0[7]=f2bf(v1.w);
            float4 u0 = *(const float4*)(ab + aoff1 + ko);
            float4 u1 = *(const float4*)(ab + aoff1 + ko + 4);
            a1[0]=f2bf(u0.x); a1[1]=f2bf(u0.y); a1[2]=f2bf(u0.z); a1[3]=f2bf(u0.w);
            a1[4]=f2bf(u1.x); a1[5]=f2bf(u1.y); a1[6]=f2bf(u1.z); a1[7]=f2bf(u1.w);
        }

#pragma unroll
        for (int fn = 0; fn < 4; ++fn) {
            acc[0][fn] = __builtin_amdgcn_mfma_f32_16x16x32_bf16(a0, bfr[fn], acc[0][fn], 0, 0, 0);
            acc[1][fn] = __builtin_amdgcn_mfma_f32_16x16x32_bf16(a1, bfr[fn], acc[1][fn], 0, 0, 0);
        }
    }

    // ---- epilogue: bias + lrelu + dot(w2) + exp + atomicAdd(segsum) ----
    float bias[4], w2v[4];
#pragma unroll
    for (int fn = 0; fn < 4; ++fn) {
        int col = hd * 64 + fn * 16 + l15;
        bias[fn] = b1[col];
        w2v[fn]  = w2[col];
    }
#pragma unroll
    for (int fm = 0; fm < 2; ++fm) {
#pragma unroll
        for (int r = 0; r < 4; ++r) {
            int row = row0 + wm * 32 + fm * 16 + lhi * 4 + r;   // C/D: row=(l>>4)*4+reg
            float p = 0.f;
#pragma unroll
            for (int fn = 0; fn < 4; ++fn) {
                float y = acc[fm][fn][r] + bias[fn];
                y = (y > 0.f) ? y : 0.01f * y;
                p += y * w2v[fn];
            }
#pragma unroll
            for (int m = 1; m < 16; m <<= 1) p += __shfl_xor(p, m);
            if (l15 == 0) {
                float e = __expf(p);
                attn[(size_t)row * 4 + hd] = e;
                atomicAdd(&segsum[index[row] * 4 + hd], e);
            }
        }
    }
}

__global__ void seg_norm(const float* __restrict__ attn, const int* __restrict__ index,
                         const float* __restrict__ segsum, float* __restrict__ out, int total) {
    int i = blockIdx.x * blockDim.x + threadIdx.x;
    if (i >= total) return;
    int e = i >> 2, h = i & 3;
    out[i] = attn[i] / (segsum[index[e] * 4 + h] + 1e-16f);
}

extern "C" void kernel_launch(void* const* d_in, const int* in_sizes, int n_in,
                              void* d_out, int out_size, void* d_ws, size_t ws_size,
                              hipStream_t stream) {
    const float* q   = (const float*)d_in[0];
    const float* k   = (const float*)d_in[1];
    const float* w1  = (const float*)d_in[2];
    const float* b1  = (const float*)d_in[3];
    const float* w2  = (const float*)d_in[4];
    const int* index = (const int*)d_in[5];

    const int nE = in_sizes[0] / 256;      // 320000
    char* ws = (char*)d_ws;
    float* attn   = (float*)ws;            ws += (size_t)nE * 4 * 4;
    float* segsum = (float*)ws;            ws += (size_t)NNODES * 4 * 4;
    short* wf     = (short*)ws;            // 256*512 bf16 = 256KB, frag-ordered
    float* out    = (float*)d_out;

    w1_frag<<<256, 64, 0, stream>>>(w1, wf);
    seg_init<<<(NNODES * 4 + 255) / 256, 256, 0, stream>>>(segsum, NNODES * 4);

    attn_gemm<<<nE / 64, 512, 0, stream>>>(q, k, wf, b1, w2, index, attn, segsum);

    int total = nE * 4;
    seg_norm<<<(total + 255) / 256, 256, 0, stream>>>(attn, index, segsum, out, total);
}

// Round 9
// 283.237 us; speedup vs baseline: 1.7333x; 1.7333x over previous
//
#include <hip/hip_runtime.h>
#include <hip/hip_bf16.h>

// GlobalAttn: x = lrelu(concat(q,k) @ w1^T + b1); attn[e,h] = x[e,h,:]·w2[h,:];
// out = segment_softmax(attn, index). E=320000, D=256, K=512, H=4, N=10000.
//
// R9 = R2's proven skeleton (gload_lds staging + plain __syncthreads; the
// hand-wait variants R3/R4/R5 all regressed, matching m131-m141) with its
// barrier count halved and LDS-byte ratio fixed:
//  * BM=64, BN=256 (full), BK=64 -> 8 K-steps (was 16): 2x MFMA per drain.
//  * Block 256 thr = 4 waves = 4 heads; wave tile 64x64; acc[4][4]=64 AGPR.
//  * LDS 80 KB dynamic: A bf16 [64][64] dbuf (8KBx2) + B bf16 [256][64]
//    dbuf (32KBx2) -> 2 blocks/CU, 2 waves/SIMD -> VGPR cap 256, NO spill
//    (R6/R7 lesson: unified VGPR/AGPR budget; watch WRITE_SIZE ~43MB).
//  * B staged via global_load_lds (linear dest + inverse-swizzled source);
//    A reg-staged (fp32->bf16 cvt), loads at step top (2 reg sets),
//    cvt+ds_write after MFMA (write-late). One __syncthreads per step.
//  * All LDS rows 128 B, 16B-slot XOR swizzle (slot ^= row&7) both sides
//    -> <=2-way conflicts (free, m136).

typedef __attribute__((ext_vector_type(8))) short bf16x8;
typedef __attribute__((ext_vector_type(4))) float f32x4;
typedef __attribute__((ext_vector_type(4))) short s16x4;

#define NNODES 10000

__device__ __forceinline__ short f2bf(float f) {
    __hip_bfloat16 h = __float2bfloat16(f);   // RNE
    return *reinterpret_cast<short*>(&h);
}

__device__ __forceinline__ void gload_lds16(const void* g, void* l) {
    __builtin_amdgcn_global_load_lds(
        (const __attribute__((address_space(1))) unsigned int*)g,
        (__attribute__((address_space(3))) unsigned int*)l, 16, 0, 0);
}

// ---- w1 fp32 [256][512] -> bf16 row-major (once per call) ----
__global__ void w1_cvt(const float* __restrict__ w1, short* __restrict__ w1b) {
    int i = (blockIdx.x * 256 + threadIdx.x) * 4;
    float4 v = *(const float4*)(w1 + i);
    s16x4 o; o[0] = f2bf(v.x); o[1] = f2bf(v.y); o[2] = f2bf(v.z); o[3] = f2bf(v.w);
    *(s16x4*)(w1b + i) = o;
}

__global__ void seg_init(float* __restrict__ segsum, int n) {
    int i = blockIdx.x * blockDim.x + threadIdx.x;
    if (i < n) segsum[i] = 0.f;
}

// ---------------- main fused GEMM + epilogue ----------------
__global__ __launch_bounds__(256, 2) void attn_gemm(
    const float* __restrict__ q, const float* __restrict__ kk_,
    const short* __restrict__ w1b, const float* __restrict__ b1,
    const float* __restrict__ w2, const int* __restrict__ index,
    float* __restrict__ attn, float* __restrict__ segsum)
{
    extern __shared__ __align__(16) short smem[];
    // layout (shorts): A0 [0,4096) A1 [4096,8192) B0 [8192,24576) B1 [24576,40960)
    short* const ldsA[2] = { smem, smem + 4096 };
    short* const ldsB[2] = { smem + 8192, smem + 24576 };

    const int tid  = threadIdx.x;
    const int lane = tid & 63;
    const int wn   = tid >> 6;        // wave = head 0..3
    const int l15  = lane & 15;
    const int lhi  = lane >> 4;
    const int row0 = blockIdx.x * 64; // 5000 blocks

    // A staging: thread t -> row rt=t>>2 (0..63), 16-float chunk ct=t&3
    const int rt = tid >> 2, ct = tid & 3;
    const size_t a_goff = (size_t)(row0 + rt) * 256 + ct * 16;
    const int a_wb0 = rt * 128 + (((ct * 2 + 0) ^ (rt & 7)) << 4);
    const int a_wb1 = rt * 128 + (((ct * 2 + 1) ^ (rt & 7)) << 4);

    // B staging: gload #i dest slot (i*256+tid) -> row d=i*32+(tid>>3),
    // 16B-chunk (tid&7); source chunk = (tid&7) ^ (d&7)
    const int b_d    = tid >> 3;                    // + i*32
    const int b_csrc = (tid & 7) ^ ((tid >> 3) & 7);
    const size_t b_goff = (size_t)b_d * 512 + b_csrc * 8;

    f32x4 acc[4][4];
#pragma unroll
    for (int i = 0; i < 4; ++i)
#pragma unroll
        for (int j = 0; j < 4; ++j) acc[i][j] = (f32x4){0.f, 0.f, 0.f, 0.f};

    float4 ar[2][4];   // two staging sets; A(j) -> set j&1 (static via unroll)

#define STAGE_B(kt, buf) {                                                      \
        char* bB = (char*)ldsB[buf];                                            \
        _Pragma("unroll")                                                       \
        for (int i2 = 0; i2 < 8; ++i2)                                          \
            gload_lds16(w1b + (size_t)i2 * 32 * 512 + b_goff + (kt) * 64,       \
                        bB + (i2 * 256 + tid) * 16);                            \
    }
#define LOADA(j) {                                                              \
        const float* bp = ((j) < 4) ? q : kk_;                                  \
        const float* p  = bp + a_goff + ((j) & 3) * 64;                         \
        ar[(j) & 1][0] = *(const float4*)p;                                     \
        ar[(j) & 1][1] = *(const float4*)(p + 4);                               \
        ar[(j) & 1][2] = *(const float4*)(p + 8);                               \
        ar[(j) & 1][3] = *(const float4*)(p + 12);                              \
    }
#define WRITE_A(j, buf) {                                                       \
        bf16x8 p0, p1;                                                          \
        float4 v0 = ar[(j) & 1][0], v1 = ar[(j) & 1][1];                        \
        float4 v2 = ar[(j) & 1][2], v3 = ar[(j) & 1][3];                        \
        p0[0]=f2bf(v0.x); p0[1]=f2bf(v0.y); p0[2]=f2bf(v0.z); p0[3]=f2bf(v0.w); \
        p0[4]=f2bf(v1.x); p0[5]=f2bf(v1.y); p0[6]=f2bf(v1.z); p0[7]=f2bf(v1.w); \
        p1[0]=f2bf(v2.x); p1[1]=f2bf(v2.y); p1[2]=f2bf(v2.z); p1[3]=f2bf(v2.w); \
        p1[4]=f2bf(v3.x); p1[5]=f2bf(v3.y); p1[6]=f2bf(v3.z); p1[7]=f2bf(v3.w); \
        *(bf16x8*)((char*)ldsA[buf] + a_wb0) = p0;                              \
        *(bf16x8*)((char*)ldsA[buf] + a_wb1) = p1;                              \
    }

    // ---- prologue ----
    STAGE_B(0, 0);
    LOADA(0);
    WRITE_A(0, 0);
    LOADA(1);
    __syncthreads();

    // ---- 8 K-steps ----
#pragma unroll
    for (int kt = 0; kt < 8; ++kt) {
        const int cur = kt & 1, nxt = cur ^ 1;
        if (kt < 7) STAGE_B(kt + 1, nxt);
        if (kt < 6) LOADA(kt + 2);           // -> set[kt&1], free after step kt-1

        // MFMA on current buffers
#pragma unroll
        for (int ks = 0; ks < 2; ++ks) {
            bf16x8 bfr[4], afr[4];
#pragma unroll
            for (int fn = 0; fn < 4; ++fn) {
                const int d = wn * 64 + fn * 16 + l15;
                bfr[fn] = *(const bf16x8*)((const char*)ldsB[cur] + d * 128 +
                           (((ks * 4 + lhi) ^ (d & 7)) << 4));
            }
#pragma unroll
            for (int fm = 0; fm < 4; ++fm) {
                const int r = fm * 16 + l15;
                afr[fm] = *(const bf16x8*)((const char*)ldsA[cur] + r * 128 +
                           (((ks * 4 + lhi) ^ (r & 7)) << 4));
            }
#pragma unroll
            for (int fm = 0; fm < 4; ++fm)
#pragma unroll
                for (int fn = 0; fn < 4; ++fn)
                    acc[fm][fn] = __builtin_amdgcn_mfma_f32_16x16x32_bf16(
                        afr[fm], bfr[fn], acc[fm][fn], 0, 0, 0);
        }

        if (kt < 7) {
            WRITE_A(kt + 1, nxt);            // from set[(kt+1)&1], loaded last step
            __syncthreads();
        }
    }
#undef STAGE_B
#undef LOADA
#undef WRITE_A

    // ---- epilogue: bias + lrelu + dot(w2) + exp + atomicAdd(segsum) ----
    float bias[4], w2v[4];
#pragma unroll
    for (int fn = 0; fn < 4; ++fn) {
        int col = wn * 64 + fn * 16 + l15;
        bias[fn] = b1[col];
        w2v[fn]  = w2[col];
    }
#pragma unroll
    for (int fm = 0; fm < 4; ++fm) {
#pragma unroll
        for (int r = 0; r < 4; ++r) {
            int row = row0 + fm * 16 + lhi * 4 + r;   // C/D: row=(l>>4)*4+reg
            float p = 0.f;
#pragma unroll
            for (int fn = 0; fn < 4; ++fn) {
                float y = acc[fm][fn][r] + bias[fn];
                y = (y > 0.f) ? y : 0.01f * y;
                p += y * w2v[fn];
            }
#pragma unroll
            for (int m = 1; m < 16; m <<= 1) p += __shfl_xor(p, m);
            if (l15 == 0) {
                float e = __expf(p);
                attn[(size_t)row * 4 + wn] = e;
                atomicAdd(&segsum[index[row] * 4 + wn], e);
            }
        }
    }
}

__global__ void seg_norm(const float* __restrict__ attn, const int* __restrict__ index,
                         const float* __restrict__ segsum, float* __restrict__ out, int total) {
    int i = blockIdx.x * blockDim.x + threadIdx.x;
    if (i >= total) return;
    int e = i >> 2, h = i & 3;
    out[i] = attn[i] / (segsum[index[e] * 4 + h] + 1e-16f);
}

extern "C" void kernel_launch(void* const* d_in, const int* in_sizes, int n_in,
                              void* d_out, int out_size, void* d_ws, size_t ws_size,
                              hipStream_t stream) {
    const float* q   = (const float*)d_in[0];
    const float* k   = (const float*)d_in[1];
    const float* w1  = (const float*)d_in[2];
    const float* b1  = (const float*)d_in[3];
    const float* w2  = (const float*)d_in[4];
    const int* index = (const int*)d_in[5];

    const int nE = in_sizes[0] / 256;      // 320000
    char* ws = (char*)d_ws;
    float* attn   = (float*)ws;            ws += (size_t)nE * 4 * 4;
    float* segsum = (float*)ws;            ws += (size_t)NNODES * 4 * 4;
    short* w1bf   = (short*)ws;            // 256*512 bf16 = 256KB
    float* out    = (float*)d_out;

    hipFuncSetAttribute((const void*)attn_gemm,
                        hipFuncAttributeMaxDynamicSharedMemorySize, 81920);

    w1_cvt<<<128, 256, 0, stream>>>(w1, w1bf);
    seg_init<<<(NNODES * 4 + 255) / 256, 256, 0, stream>>>(segsum, NNODES * 4);

    attn_gemm<<<nE / 64, 256, 81920, stream>>>(q, k, w1bf, b1, w2, index, attn, segsum);

    int total = nE * 4;
    seg_norm<<<(total + 255) / 256, 256, 0, stream>>>(attn, index, segsum, out, total);
}